// Round 4
// baseline (225.635 us; speedup 1.0000x reference)
//
#include <hip/hip_runtime.h>

// 16-qubit statevector, iSWAP(t) on qubits (3,7), qubit 0 = MSB.
// bit positions: qubit 3 -> bit 12, qubit 7 -> bit 8.
constexpr int DIM    = 1 << 16;    // 65536
constexpr int BATCH  = 256;        // f32 per row; 64 float4
constexpr int COLS   = BATCH / 4;  // 64 float4 columns per row
constexpr int BIT_HI = 1 << 12;    // qubit 3
constexpr int BIT_LO = 1 << 8;     // qubit 7

constexpr int NFREE = DIM / 4;            // 16384 free (non-target) index values
constexpr int TOTAL = NFREE * COLS;       // 1,048,576 threads, one per (f, col)

// Clang native vector type: __builtin_nontemporal_* requires a native
// vector, not HIP's float4 class.
typedef float v4f __attribute__((ext_vector_type(4)));

// Insert 14 low bits of b into positions {0..7, 9..11, 13..15}
// (leaves bits 8 and 12 zero).
__device__ __forceinline__ int expand14(int b) {
    return (b & 0x00FF) | ((b & 0x0700) << 1) | ((b & 0x3800) << 2);
}

__global__ __launch_bounds__(256) void iswap_kernel(
    const float* __restrict__ sr, const float* __restrict__ si,
    const float* __restrict__ tp, float* __restrict__ out)
{
    const int gid = blockIdx.x * blockDim.x + threadIdx.x;
    float* __restrict__ out_r = out;
    float* __restrict__ out_i = out + (size_t)DIM * BATCH;

    // Fast trig: t in [0, 2pi), threshold 0.108 -> __sinf/__cosf suffice.
    const float tv = tp[0];
    const float s = __sinf(tv);
    const float c = __cosf(tv);

    const int col  = gid & (COLS - 1);
    const int f    = gid >> 6;               // [0, NFREE)
    const int base = expand14(f);            // b12=0, b8=0
    const size_t cb  = (size_t)col * 4;
    const size_t o00 = (size_t)base * BATCH + cb;
    const size_t o01 = o00 + (size_t)BIT_LO * BATCH;
    const size_t o10 = o00 + (size_t)BIT_HI * BATCH;
    const size_t o11 = o00 + (size_t)(BIT_HI | BIT_LO) * BATCH;

    // Streaming data, zero reuse: nontemporal everywhere. 8 loads in
    // flight per thread for latency hiding.
    const v4f r00 = __builtin_nontemporal_load((const v4f*)(sr + o00));
    const v4f m00 = __builtin_nontemporal_load((const v4f*)(si + o00));
    const v4f r01 = __builtin_nontemporal_load((const v4f*)(sr + o01));
    const v4f m01 = __builtin_nontemporal_load((const v4f*)(si + o01));
    const v4f r10 = __builtin_nontemporal_load((const v4f*)(sr + o10));
    const v4f m10 = __builtin_nontemporal_load((const v4f*)(si + o10));
    const v4f r11 = __builtin_nontemporal_load((const v4f*)(sr + o11));
    const v4f m11 = __builtin_nontemporal_load((const v4f*)(si + o11));

    // (0,0) and (1,1): identity. (0,1)/(1,0): c/-is mix.
    // re(new01) = c*r01 + s*m10 ; im(new01) = c*m01 - s*r10  (symmetric for 10)
    const v4f nr01 = c * r01 + s * m10;
    const v4f ni01 = c * m01 - s * r10;
    const v4f nr10 = c * r10 + s * m01;
    const v4f ni10 = c * m10 - s * r01;

    __builtin_nontemporal_store(r00,  (v4f*)(out_r + o00));
    __builtin_nontemporal_store(m00,  (v4f*)(out_i + o00));
    __builtin_nontemporal_store(nr01, (v4f*)(out_r + o01));
    __builtin_nontemporal_store(ni01, (v4f*)(out_i + o01));
    __builtin_nontemporal_store(nr10, (v4f*)(out_r + o10));
    __builtin_nontemporal_store(ni10, (v4f*)(out_i + o10));
    __builtin_nontemporal_store(r11,  (v4f*)(out_r + o11));
    __builtin_nontemporal_store(m11,  (v4f*)(out_i + o11));
}

extern "C" void kernel_launch(void* const* d_in, const int* in_sizes, int n_in,
                              void* d_out, int out_size, void* d_ws, size_t ws_size,
                              hipStream_t stream) {
    const float* sr = (const float*)d_in[0];
    const float* si = (const float*)d_in[1];
    const float* t  = (const float*)d_in[2];
    float* out = (float*)d_out;

    static_assert(TOTAL % 256 == 0, "grid sizing");
    iswap_kernel<<<dim3(TOTAL / 256), dim3(256), 0, stream>>>(sr, si, t, out);
}